// Round 1
// baseline (108.853 us; speedup 1.0000x reference)
//
#include <hip/hip_runtime.h>
#include <hip/hip_bf16.h>

typedef __attribute__((ext_vector_type(8)))  __bf16 bf16x8;
typedef __attribute__((ext_vector_type(4)))  __bf16 bf16x4;
typedef __attribute__((ext_vector_type(16))) float  f32x16;
typedef __attribute__((ext_vector_type(4)))  float  f32x4;

#define B_    32
#define CIN   512
#define HID   256
#define HW    4096
#define NA    9
#define NCH   65      // 5*9 + 20
#define NPADC 96      // padded output channels for GEMM2 (3 x 32)
#define BN    128     // spatial tile per block
#define M_    65536
#define NTOT  (B_*NA*HW)   // 1179648

// Workspace layout (bytes):
//   [0)         W1bt  bf16 [16][256][32]   262144   (K-tiled for coalesced staging)
//   [262144)    W2p   bf16 [96][256]        49152   (rows >=65 zero)
//   [311296)    conf_dense f32 [NTOT]     4718592
//   [5029888)   off_dense  f32 [4][NTOT] 18874368   (planar: coalesced epilogue writes)
//   [23904256)  cls_dense  f32 [B*HW][20]10485760  (position-major: 2-line gathers)
//   total 34390016

static __device__ __forceinline__ float sigf(float v) {
    return 1.f / (1.f + __expf(-v));
}

__global__ void prep_weights(const float* __restrict__ W1, const float* __restrict__ W2,
                             unsigned short* __restrict__ W1bt, unsigned short* __restrict__ W2p) {
    int i = blockIdx.x * 256 + threadIdx.x;
    if (i < 16*256*32) {
        int kt = i >> 13, o = (i >> 5) & 255, kk = i & 31;
        __bf16 h = (__bf16)W1[o*CIN + kt*32 + kk];
        W1bt[i] = __builtin_bit_cast(unsigned short, h);
    } else {
        int j = i - 16*256*32;
        if (j < NPADC*HID) {
            int o = j >> 8, c = j & 255;
            float v = (o < NCH) ? W2[o*HID + c] : 0.f;
            __bf16 h = (__bf16)v;
            W2p[j] = __builtin_bit_cast(unsigned short, h);
        }
    }
}

// 4 waves. GEMM1: h[256][128] = W1[256x512] @ F[512x128]; wave tile 64(M)x128(N).
// Then h -> LDS (bf16, XOR-swizzled, 64KB union), GEMM2: out[96][128] = W2p @ h.
__launch_bounds__(256, 2)
__global__ void fused_mlp(const float* __restrict__ feat,
                          const float* __restrict__ b1,
                          const float* __restrict__ b2,
                          const unsigned short* __restrict__ W1bt,
                          const unsigned short* __restrict__ W2p,
                          float* __restrict__ conf_d,
                          float* __restrict__ off_d,
                          float* __restrict__ cls_d) {
    // union: [0,20480) A-stage bf16[256][40]; [20480,30720) B-stage bf16[128][40];
    //        after GEMM1: whole 64KB is hT bf16 (col*512 + row*2) ^ ((col&7)<<4)
    __shared__ __align__(16) unsigned char smem[65536];
    unsigned short* As = (unsigned short*)smem;               // [256][40] padded
    unsigned short* Bs = (unsigned short*)(smem + 20480);     // [128][40] padded (transposed: [spatial][k])

    const int tid  = threadIdx.x;
    const int w    = tid >> 6;         // wave id
    const int lane = tid & 63;
    const int lr   = lane & 31;
    const int lh   = lane >> 5;
    const int bidx = blockIdx.x >> 5;          // batch
    const int hw0  = (blockIdx.x & 31) * BN;   // spatial tile base

    const float* fb = feat + (size_t)bidx * CIN * HW + hw0;

    const int sA  = tid;              // A staging: one W1 row per thread
    const int sB  = tid & 127;        // B staging: spatial column
    const int kgB = tid >> 7;         // k-group 0/1 (handles kgB and kgB+2)

    f32x16 acc[2][4];
#pragma unroll
    for (int m = 0; m < 2; ++m)
#pragma unroll
        for (int n = 0; n < 4; ++n) acc[m][n] = (f32x16)0.f;

    bf16x8 pa[4];
    float  pb[16];

    auto loadA = [&](int kt) {
        const bf16x8* p = (const bf16x8*)(W1bt + kt*8192 + sA*32);
#pragma unroll
        for (int i = 0; i < 4; ++i) pa[i] = p[i];
    };
    auto loadB = [&](int kt) {
#pragma unroll
        for (int q = 0; q < 2; ++q) {
            int kg = kgB + 2*q;
            const float* src = fb + (size_t)(kt*32 + kg*8) * HW + sB;
#pragma unroll
            for (int j = 0; j < 8; ++j) pb[q*8 + j] = src[(size_t)j * HW];
        }
    };
    auto storeAB = [&]() {
#pragma unroll
        for (int i = 0; i < 4; ++i) *(bf16x8*)(As + sA*40 + i*8) = pa[i];
#pragma unroll
        for (int q = 0; q < 2; ++q) {
            int kg = kgB + 2*q;
            bf16x8 v8;
#pragma unroll
            for (int j = 0; j < 8; ++j) v8[j] = (__bf16)pb[q*8 + j];
            *(bf16x8*)(Bs + sB*40 + kg*8) = v8;   // transposed: row=spatial, col=k
        }
    };

    loadA(0); loadB(0);
    for (int kt = 0; kt < 16; ++kt) {
        storeAB();
        __syncthreads();
        if (kt < 15) { loadA(kt + 1); loadB(kt + 1); }   // overlap with MFMA
#pragma unroll
        for (int kk = 0; kk < 2; ++kk) {
            bf16x8 a0 = *(const bf16x8*)(As + (64*w      + lr)*40 + kk*16 + lh*8);
            bf16x8 a1 = *(const bf16x8*)(As + (64*w + 32 + lr)*40 + kk*16 + lh*8);
#pragma unroll
            for (int n = 0; n < 4; ++n) {
                bf16x8 bv = *(const bf16x8*)(Bs + (32*n + lr)*40 + kk*16 + lh*8);
                acc[0][n] = __builtin_amdgcn_mfma_f32_32x32x16_bf16(a0, bv, acc[0][n], 0, 0, 0);
                acc[1][n] = __builtin_amdgcn_mfma_f32_32x32x16_bf16(a1, bv, acc[1][n], 0, 0, 0);
            }
        }
        __syncthreads();
    }

    // ---- epilogue 1: h = leaky(h + b1) -> hT in LDS (bf16, swizzled) ----
#pragma unroll
    for (int m = 0; m < 2; ++m)
#pragma unroll
        for (int n = 0; n < 4; ++n) {
            int col = 32*n + lr;
            unsigned cswz = (unsigned)((col & 7) << 4);
#pragma unroll
            for (int g = 0; g < 4; ++g) {
                int rbase = 64*w + 32*m + 8*g + 4*lh;        // h row (HID channel)
                f32x4 b1v = *(const f32x4*)(b1 + rbase);
                bf16x4 pk;
#pragma unroll
                for (int r = 0; r < 4; ++r) {
                    float v = acc[m][n][4*g + r] + b1v[r];
                    v = v > 0.f ? v : 0.01f * v;
                    pk[r] = (__bf16)v;
                }
                unsigned addr = (unsigned)(col*512 + rbase*2) ^ cswz;
                *(bf16x4*)(smem + addr) = pk;
            }
        }
    __syncthreads();

    // ---- GEMM2: out[96][128] = W2p[96][256] @ h[256][128]; wave owns 32 cols ----
    f32x16 acc2[3];
#pragma unroll
    for (int m = 0; m < 3; ++m) acc2[m] = (f32x16)0.f;
    const int col2 = 32*w + lr;
    const unsigned cswz2 = (unsigned)((col2 & 7) << 4);
    for (int kt2 = 0; kt2 < 8; ++kt2) {
#pragma unroll
        for (int kk = 0; kk < 2; ++kk) {
            int k0 = kt2*32 + kk*16 + lh*8;
            bf16x8 bv = *(const bf16x8*)(smem + ((unsigned)(col2*512 + k0*2) ^ cswz2));
#pragma unroll
            for (int m = 0; m < 3; ++m) {
                bf16x8 av = *(const bf16x8*)(W2p + (32*m + lr)*256 + k0);
                acc2[m] = __builtin_amdgcn_mfma_f32_32x32x16_bf16(av, bv, acc2[m], 0, 0, 0);
            }
        }
    }

    // ---- epilogue 2: activations + dense scatter ----
    const int hw     = hw0 + col2;
    const int b9     = bidx * NA;
    const int posIdx = (bidx << 12) + hw;   // b*4096 + hw
#pragma unroll
    for (int m = 0; m < 3; ++m)
#pragma unroll
        for (int g = 0; g < 4; ++g) {
            int rbase = 32*m + 8*g + 4*lh;
#pragma unroll
            for (int r = 0; r < 4; ++r) {
                int row = rbase + r;                    // output channel
                if (row >= NCH) continue;
                float v = acc2[m][4*g + r] + b2[row];
                if (row < 45) {
                    int a = row / 5;
                    int j = row - a*5;
                    int abase = ((b9 + a) << 12) + hw;
                    if (j == 0)      conf_d[abase] = sigf(v);
                    else if (j <= 2) off_d[(j-1)*NTOT + abase] = sigf(v) - 0.5f;
                    else             off_d[(j-1)*NTOT + abase] = v;
                } else {
                    cls_d[posIdx*20 + (row - 45)] = v;
                }
            }
        }
}

__global__ void gather_k(const int* __restrict__ pos, const int* __restrict__ neg,
                         const float* __restrict__ conf_d, const float* __restrict__ off_d,
                         const float* __restrict__ cls_d, float* __restrict__ out) {
    int i = blockIdx.x * 256 + threadIdx.x;
    if (i >= M_) return;
    int p = pos[i], q = neg[i];
    out[i]      = conf_d[p];
    out[M_ + i] = conf_d[q];
    f32x4 o;
    o[0] = off_d[p];
    o[1] = off_d[NTOT + p];
    o[2] = off_d[2*NTOT + p];
    o[3] = off_d[3*NTOT + p];
    *(f32x4*)(out + 2*M_ + 4*i) = o;
    int hw = p & 4095;
    int ba = p >> 12;        // b*9 + a
    int b  = ba / 9;
    const f32x4* c4 = (const f32x4*)(cls_d + (size_t)(b*4096 + hw) * 20);
    f32x4* o4 = (f32x4*)(out + 6*M_ + 20*i);
#pragma unroll
    for (int t = 0; t < 5; ++t) o4[t] = c4[t];
}

extern "C" void kernel_launch(void* const* d_in, const int* in_sizes, int n_in,
                              void* d_out, int out_size, void* d_ws, size_t ws_size,
                              hipStream_t stream) {
    const float* feat = (const float*)d_in[0];
    const float* W1   = (const float*)d_in[1];
    const float* b1   = (const float*)d_in[2];
    const float* W2   = (const float*)d_in[3];
    const float* b2   = (const float*)d_in[4];
    const int*   pos  = (const int*)d_in[5];
    const int*   neg  = (const int*)d_in[6];
    float* out = (float*)d_out;

    char* ws = (char*)d_ws;
    unsigned short* W1bt = (unsigned short*)ws;
    unsigned short* W2p  = (unsigned short*)(ws + 262144);
    float* conf_d = (float*)(ws + 311296);
    float* off_d  = (float*)(ws + 5029888);
    float* cls_d  = (float*)(ws + 23904256);

    prep_weights<<<608, 256, 0, stream>>>(W1, W2, W1bt, W2p);
    fused_mlp<<<1024, 256, 0, stream>>>(feat, b1, b2, W1bt, W2p, conf_d, off_d, cls_d);
    gather_k<<<256, 256, 0, stream>>>(pos, neg, conf_d, off_d, cls_d, out);
}

// Round 2
// 96.049 us; speedup vs baseline: 1.1333x; 1.1333x over previous
//
#include <hip/hip_runtime.h>
#include <hip/hip_bf16.h>

typedef __attribute__((ext_vector_type(8)))  __bf16 bf16x8;
typedef __attribute__((ext_vector_type(4)))  __bf16 bf16x4;
typedef __attribute__((ext_vector_type(16))) float  f32x16;
typedef __attribute__((ext_vector_type(4)))  float  f32x4;

#define B_    32
#define CIN   512
#define HID   256
#define HW    4096
#define NA    9
#define NCH   65      // 5*9 + 20
#define NPADC 96      // padded output channels for GEMM2 (3 x 32)
#define BN    128     // spatial tile per block
#define M_    65536
#define NTOT  (B_*NA*HW)   // 1179648

// Workspace layout (bytes):
//   [0)         W1bt  bf16 [16][256][32]     262144  (K-tiled, coalesced staging)
//   [262144)    W2p   bf16 [96][256]          49152  (rows >=65 zero)
//   [311296)    conf_d f32  [NTOT]          4718592
//   [5029888)   off_w  bf16 [NTOT][4]       9437184  (interleaved: 8B = 1-line gather)
//   [14467072)  cls_w  bf16 [B*HW][32]      8388608  (64B-aligned full-sector rows)
//   total ~22.9 MB

static __device__ __forceinline__ float sigf(float v) {
    return 1.f / (1.f + __expf(-v));
}

__global__ void prep_weights(const float* __restrict__ W1, const float* __restrict__ W2,
                             unsigned short* __restrict__ W1bt, unsigned short* __restrict__ W2p) {
    int i = blockIdx.x * 256 + threadIdx.x;
    if (i < 16*256*32) {
        int kt = i >> 13, o = (i >> 5) & 255, kk = i & 31;
        __bf16 h = (__bf16)W1[o*CIN + kt*32 + kk];
        W1bt[i] = __builtin_bit_cast(unsigned short, h);
    } else {
        int j = i - 16*256*32;
        if (j < NPADC*HID) {
            int o = j >> 8, c = j & 255;
            float v = (o < NCH) ? W2[o*HID + c] : 0.f;
            __bf16 h = (__bf16)v;
            W2p[j] = __builtin_bit_cast(unsigned short, h);
        }
    }
}

// 4 waves. GEMM1: h[256][128] = W1[256x512] @ F[512x128]; wave tile 64(M)x128(N).
// Then h -> LDS (bf16, XOR-swizzled, 64KB union), GEMM2: out[96][128] = W2p @ h,
// then out-tile staged in LDS (f32 [96][128]) and packed per-position.
__launch_bounds__(256, 2)
__global__ void fused_mlp(const float* __restrict__ feat,
                          const float* __restrict__ b1,
                          const float* __restrict__ b2,
                          const unsigned short* __restrict__ W1bt,
                          const unsigned short* __restrict__ W2p,
                          float* __restrict__ conf_d,
                          unsigned short* __restrict__ off_w,
                          unsigned short* __restrict__ cls_w) {
    // union: [0,20480) A-stage bf16[256][40]; [20480,30720) B-stage bf16[128][40];
    //        after GEMM1: 64KB hT bf16 (col*512 + row*2) ^ ((col&7)<<4);
    //        after GEMM2: f32 out-stage [96][128] (48KB)
    __shared__ __align__(16) unsigned char smem[65536];
    unsigned short* As = (unsigned short*)smem;               // [256][40] padded
    unsigned short* Bs = (unsigned short*)(smem + 20480);     // [128][40] padded ([spatial][k])

    const int tid  = threadIdx.x;
    const int w    = tid >> 6;         // wave id
    const int lane = tid & 63;
    const int lr   = lane & 31;
    const int lh   = lane >> 5;
    const int bidx = blockIdx.x >> 5;          // batch
    const int hw0  = (blockIdx.x & 31) * BN;   // spatial tile base

    const float* fb = feat + (size_t)bidx * CIN * HW + hw0;

    const int sA  = tid;              // A staging: one W1 row per thread
    const int sB  = tid & 127;        // B staging: spatial column
    const int kgB = tid >> 7;         // k-group 0/1 (handles kgB and kgB+2)

    f32x16 acc[2][4];
#pragma unroll
    for (int m = 0; m < 2; ++m)
#pragma unroll
        for (int n = 0; n < 4; ++n) acc[m][n] = (f32x16)0.f;

    bf16x8 pa[4];
    float  pb[16];

    auto loadA = [&](int kt) {
        const bf16x8* p = (const bf16x8*)(W1bt + kt*8192 + sA*32);
#pragma unroll
        for (int i = 0; i < 4; ++i) pa[i] = p[i];
    };
    auto loadB = [&](int kt) {
#pragma unroll
        for (int q = 0; q < 2; ++q) {
            int kg = kgB + 2*q;
            const float* src = fb + (size_t)(kt*32 + kg*8) * HW + sB;
#pragma unroll
            for (int j = 0; j < 8; ++j) pb[q*8 + j] = src[(size_t)j * HW];
        }
    };
    auto storeAB = [&]() {
#pragma unroll
        for (int i = 0; i < 4; ++i) *(bf16x8*)(As + sA*40 + i*8) = pa[i];
#pragma unroll
        for (int q = 0; q < 2; ++q) {
            int kg = kgB + 2*q;
            bf16x8 v8;
#pragma unroll
            for (int j = 0; j < 8; ++j) v8[j] = (__bf16)pb[q*8 + j];
            *(bf16x8*)(Bs + sB*40 + kg*8) = v8;   // transposed: row=spatial, col=k
        }
    };

    loadA(0); loadB(0);
    for (int kt = 0; kt < 16; ++kt) {
        storeAB();
        __syncthreads();
        if (kt < 15) { loadA(kt + 1); loadB(kt + 1); }   // overlap with MFMA
#pragma unroll
        for (int kk = 0; kk < 2; ++kk) {
            bf16x8 a0 = *(const bf16x8*)(As + (64*w      + lr)*40 + kk*16 + lh*8);
            bf16x8 a1 = *(const bf16x8*)(As + (64*w + 32 + lr)*40 + kk*16 + lh*8);
#pragma unroll
            for (int n = 0; n < 4; ++n) {
                bf16x8 bv = *(const bf16x8*)(Bs + (32*n + lr)*40 + kk*16 + lh*8);
                acc[0][n] = __builtin_amdgcn_mfma_f32_32x32x16_bf16(a0, bv, acc[0][n], 0, 0, 0);
                acc[1][n] = __builtin_amdgcn_mfma_f32_32x32x16_bf16(a1, bv, acc[1][n], 0, 0, 0);
            }
        }
        __syncthreads();
    }

    // ---- epilogue 1: h = leaky(h + b1) -> hT in LDS (bf16, swizzled) ----
#pragma unroll
    for (int m = 0; m < 2; ++m)
#pragma unroll
        for (int n = 0; n < 4; ++n) {
            int col = 32*n + lr;
            unsigned cswz = (unsigned)((col & 7) << 4);
#pragma unroll
            for (int g = 0; g < 4; ++g) {
                int rbase = 64*w + 32*m + 8*g + 4*lh;        // h row (HID channel)
                f32x4 b1v = *(const f32x4*)(b1 + rbase);
                bf16x4 pk;
#pragma unroll
                for (int r = 0; r < 4; ++r) {
                    float v = acc[m][n][4*g + r] + b1v[r];
                    v = v > 0.f ? v : 0.01f * v;
                    pk[r] = (__bf16)v;
                }
                unsigned addr = (unsigned)(col*512 + rbase*2) ^ cswz;
                *(bf16x4*)(smem + addr) = pk;
            }
        }
    __syncthreads();

    // ---- GEMM2: out[96][128] = W2p[96][256] @ h[256][128]; wave owns 32 cols ----
    f32x16 acc2[3];
#pragma unroll
    for (int m = 0; m < 3; ++m) acc2[m] = (f32x16)0.f;
    const int col2 = 32*w + lr;
    const unsigned cswz2 = (unsigned)((col2 & 7) << 4);
    for (int kt2 = 0; kt2 < 8; ++kt2) {
#pragma unroll
        for (int kk = 0; kk < 2; ++kk) {
            int k0 = kt2*32 + kk*16 + lh*8;
            bf16x8 bv = *(const bf16x8*)(smem + ((unsigned)(col2*512 + k0*2) ^ cswz2));
#pragma unroll
            for (int m = 0; m < 3; ++m) {
                bf16x8 av = *(const bf16x8*)(W2p + (32*m + lr)*256 + k0);
                acc2[m] = __builtin_amdgcn_mfma_f32_32x32x16_bf16(av, bv, acc2[m], 0, 0, 0);
            }
        }
    }

    // ---- epilogue 2: stage out-tile f32 [96][128] in LDS ----
    __syncthreads();    // all waves done reading hT
    float* so = (float*)smem;
#pragma unroll
    for (int m = 0; m < 3; ++m)
#pragma unroll
        for (int g = 0; g < 4; ++g) {
            int rbase = 32*m + 8*g + 4*lh;
            if (rbase <= 64) {
#pragma unroll
                for (int r = 0; r < 4; ++r) {
                    int row = rbase + r;
                    if (row < NCH) so[row*128 + col2] = acc2[m][4*g + r] + b2[row];
                }
            }
        }
    __syncthreads();

    // ---- epilogue 3: per-position pack + coalesced dense writes ----
    {
        const int p   = tid & 127;
        const int phw = hw0 + p;
        const int b9  = bidx * NA;
        if (tid < 128) {
            // waves 0-1: conf (f32 planar) + off (bf16x4 interleaved, 8B/anchor)
#pragma unroll
            for (int a = 0; a < 9; ++a) {
                float v0 = so[(5*a+0)*128 + p];
                float v1 = so[(5*a+1)*128 + p];
                float v2 = so[(5*a+2)*128 + p];
                float v3 = so[(5*a+3)*128 + p];
                float v4 = so[(5*a+4)*128 + p];
                int abase = ((b9 + a) << 12) + phw;
                conf_d[abase] = sigf(v0);
                bf16x4 o;
                o[0] = (__bf16)(sigf(v1) - 0.5f);
                o[1] = (__bf16)(sigf(v2) - 0.5f);
                o[2] = (__bf16)v3;
                o[3] = (__bf16)v4;
                *(bf16x4*)(off_w + ((size_t)abase << 2)) = o;
            }
        } else {
            // waves 2-3: cls, full 64B sector per position (pad rows 20..31 = 0)
            unsigned short* dst = cls_w + ((size_t)((bidx << 12) + phw) << 5);
#pragma unroll
            for (int q = 0; q < 4; ++q) {
                bf16x8 v;
#pragma unroll
                for (int r = 0; r < 8; ++r) {
                    int c = q*8 + r;
                    v[r] = (c < 20) ? (__bf16)so[(45 + c)*128 + p] : (__bf16)0.f;
                }
                *(bf16x8*)(dst + q*8) = v;
            }
        }
    }
}

// roles by block range (uniform): [0,2M) conf pos|neg ; [2M,3M) off ; [3M,4M) cls
__global__ void gather_all(const int* __restrict__ pos, const int* __restrict__ neg,
                           const float* __restrict__ conf_d,
                           const unsigned short* __restrict__ off_w,
                           const unsigned short* __restrict__ cls_w,
                           float* __restrict__ out) {
    int t = blockIdx.x * 256 + threadIdx.x;
    if (t < 2*M_) {
        int idx = (t < M_) ? pos[t] : neg[t - M_];
        out[t] = conf_d[idx];
    } else if (t < 3*M_) {
        int i = t - 2*M_;
        int p = pos[i];
        bf16x4 o = *(const bf16x4*)(off_w + ((size_t)p << 2));
        f32x4 f;
        f[0] = (float)o[0]; f[1] = (float)o[1];
        f[2] = (float)o[2]; f[3] = (float)o[3];
        *(f32x4*)(out + 2*(size_t)M_ + 4*(size_t)i) = f;
    } else {
        int i = t - 3*M_;
        int p = pos[i];
        int hw = p & 4095;
        int b  = (p >> 12) / 9;
        const unsigned short* src = cls_w + ((size_t)((b << 12) + hw) << 5);
        float* dst = out + 6*(size_t)M_ + 20*(size_t)i;
        bf16x8 v0 = *(const bf16x8*)(src);
        bf16x8 v1 = *(const bf16x8*)(src + 8);
        bf16x4 v2 = *(const bf16x4*)(src + 16);
        f32x4 f;
        f[0] = (float)v0[0]; f[1] = (float)v0[1]; f[2] = (float)v0[2]; f[3] = (float)v0[3];
        *(f32x4*)(dst) = f;
        f[0] = (float)v0[4]; f[1] = (float)v0[5]; f[2] = (float)v0[6]; f[3] = (float)v0[7];
        *(f32x4*)(dst + 4) = f;
        f[0] = (float)v1[0]; f[1] = (float)v1[1]; f[2] = (float)v1[2]; f[3] = (float)v1[3];
        *(f32x4*)(dst + 8) = f;
        f[0] = (float)v1[4]; f[1] = (float)v1[5]; f[2] = (float)v1[6]; f[3] = (float)v1[7];
        *(f32x4*)(dst + 12) = f;
        f[0] = (float)v2[0]; f[1] = (float)v2[1]; f[2] = (float)v2[2]; f[3] = (float)v2[3];
        *(f32x4*)(dst + 16) = f;
    }
}

extern "C" void kernel_launch(void* const* d_in, const int* in_sizes, int n_in,
                              void* d_out, int out_size, void* d_ws, size_t ws_size,
                              hipStream_t stream) {
    const float* feat = (const float*)d_in[0];
    const float* W1   = (const float*)d_in[1];
    const float* b1   = (const float*)d_in[2];
    const float* W2   = (const float*)d_in[3];
    const float* b2   = (const float*)d_in[4];
    const int*   pos  = (const int*)d_in[5];
    const int*   neg  = (const int*)d_in[6];
    float* out = (float*)d_out;

    char* ws = (char*)d_ws;
    unsigned short* W1bt = (unsigned short*)ws;
    unsigned short* W2p  = (unsigned short*)(ws + 262144);
    float*          conf_d = (float*)(ws + 311296);
    unsigned short* off_w  = (unsigned short*)(ws + 5029888);
    unsigned short* cls_w  = (unsigned short*)(ws + 14467072);

    prep_weights<<<608, 256, 0, stream>>>(W1, W2, W1bt, W2p);
    fused_mlp<<<1024, 256, 0, stream>>>(feat, b1, b2, W1bt, W2p, conf_d, off_w, cls_w);
    gather_all<<<1024, 256, 0, stream>>>(pos, neg, conf_d, off_w, cls_w, out);
}